// Round 16
// baseline (971.616 us; speedup 1.0000x reference)
//
#include <hip/hip_runtime.h>
#include <math.h>

// BiLSTM-CRF fp32, round 16.
// rstep v6: acc[8] / 1024 blocks / launch_bounds(512,8) -> 8 waves/SIMD
// (2x v4 occupancy; rstep is latency-bound on the uniform-h s_load drains).
// ggemm round-9 (222us), viterbi v4, prep/out unchanged (all proven).
// Output: d_out[0:32]=score, d_out[32:32+16384]=path (floats).

namespace {

constexpr int T_ = 11;
constexpr int HT = 256 * 512;        // one h slab (j-major, s-innermost)

__device__ __forceinline__ size_t gq_off(int t, int d, int j, int q, int s) {
  return ((((size_t)(t * 2 + d) * 256 + j) * 4 + q) * 512 + s);
}

__device__ __forceinline__ float rdlane(float v, int l) {
  return __uint_as_float(__builtin_amdgcn_readlane(__float_as_uint(v), l));
}

// ---------------- K0: prep (transposes), flat 1,580,544 elements ----------------
__global__ __launch_bounds__(256) void k_prep(
    const float* __restrict__ w_ih_f, const float* __restrict__ w_ih_b,
    const float* __restrict__ w_hh_f, const float* __restrict__ w_hh_b,
    const float* __restrict__ b_ih_f, const float* __restrict__ b_hh_f,
    const float* __restrict__ b_ih_b, const float* __restrict__ b_hh_b,
    const float* __restrict__ h0, const float* __restrict__ c0,
    const float* __restrict__ w_out,
    float* __restrict__ wiq, float* __restrict__ wt4, float* __restrict__ bq,
    float* __restrict__ ct, float* __restrict__ ht_f, float* __restrict__ ht_b,
    float* __restrict__ wot) {
  const int i = blockIdx.x * 256 + threadIdx.x;
  if (i < 524288) {                                    // wiq from w_ih
    int d = i >> 18, r = i & 262143, gcr = r >> 8, k = r & 255;
    int q = gcr >> 8, j = gcr & 255;
    const float* w = d ? w_ih_b : w_ih_f;
    wiq[((size_t)(d * 256 + k) * 256 + j) * 4 + q] = w[gcr * 256 + k];
  } else if (i < 1048576) {                            // wt4 from w_hh (same fmt)
    int i2 = i - 524288;
    int d = i2 >> 18, r = i2 & 262143, gcr = r >> 8, k = r & 255;
    int q = gcr >> 8, j = gcr & 255;
    const float* w = d ? w_hh_b : w_hh_f;
    wt4[((size_t)(d * 256 + k) * 256 + j) * 4 + q] = w[gcr * 256 + k];
  } else if (i < 1050624) {                            // bq
    int r = i - 1048576;
    int d = r >> 10, x = r & 1023, j = x >> 2, q = x & 3;
    const float* bi = d ? b_ih_b : b_ih_f;
    const float* bh = d ? b_hh_b : b_hh_f;
    bq[r] = bi[q * 256 + j] + bh[q * 256 + j];
  } else if (i < 1312768) {                            // ct from c0
    int r = i - 1050624;
    int d = r >> 17, y = r & 131071, j = y >> 9, s = y & 511;
    ct[r] = c0[((size_t)d * 512 + s) * 256 + j];
  } else if (i < 1574912) {                            // ht slot 0 from h0
    int r = i - 1312768;
    int d = r >> 17, y = r & 131071, j = y >> 9, s = y & 511;
    float v = h0[((size_t)d * 512 + s) * 256 + j];
    if (d == 0) ht_f[y] = v; else ht_b[y] = v;
  } else if (i < 1580544) {                            // wot from w_out
    int r = i - 1574912;
    int k = r / 11, tag = r - k * 11;
    wot[r] = w_out[tag * 512 + k];
  }
}

// ---------------- K1: Gq = x@W_ih^T + bias (round-9 version, proven 222us) ----------------
__global__ __launch_bounds__(256) void k_ggemm(
    const int* __restrict__ sent, const float* __restrict__ embed,
    const float* __restrict__ wiq, const float* __restrict__ bq,
    float* __restrict__ Gq) {
  __shared__ float As[64][67];
  const int tid = threadIdx.x;
  const int bid = blockIdx.x;
  const int jg4 = bid & 15;
  const int d = (bid >> 4) & 1;
  const int rt = bid >> 5;
  const int wid = __builtin_amdgcn_readfirstlane(tid >> 6);
  const int lane = tid & 63;
  const int row0 = rt * 64;
  const int t = row0 >> 9;
  const int sb = (row0 & 511) + lane;
  const int j0 = (jg4 * 4 + wid) * 4;

  const int rr = tid & 63, eq = tid >> 6;
  const int tok = sent[row0 + rr];
  const float* erow = embed + (size_t)tok * 256 + eq * 16;

  float acc[16];
#pragma unroll
  for (int g = 0; g < 16; ++g) acc[g] = 0.f;

  const float* wbase = wiq + (size_t)d * 256 * 1024;

  for (int ci = 0; ci < 4; ++ci) {
    const int k0 = ci * 64;
    const float* ep = erow + k0;
    float4 v0 = *(const float4*)(ep);
    float4 v1 = *(const float4*)(ep + 4);
    float4 v2 = *(const float4*)(ep + 8);
    float4 v3 = *(const float4*)(ep + 12);
    const int kb = eq * 16;
    As[kb + 0][rr] = v0.x;  As[kb + 1][rr] = v0.y;  As[kb + 2][rr] = v0.z;  As[kb + 3][rr] = v0.w;
    As[kb + 4][rr] = v1.x;  As[kb + 5][rr] = v1.y;  As[kb + 6][rr] = v1.z;  As[kb + 7][rr] = v1.w;
    As[kb + 8][rr] = v2.x;  As[kb + 9][rr] = v2.y;  As[kb + 10][rr] = v2.z; As[kb + 11][rr] = v2.w;
    As[kb + 12][rr] = v3.x; As[kb + 13][rr] = v3.y; As[kb + 14][rr] = v3.z; As[kb + 15][rr] = v3.w;
    __syncthreads();
#pragma unroll 4
    for (int kk = 0; kk < 64; ++kk) {
      float a = As[kk][lane];
      const float* wp = wbase + (size_t)(k0 + kk) * 1024 + j0 * 4;  // uniform
#pragma unroll
      for (int g = 0; g < 16; ++g) acc[g] = fmaf(a, wp[g], acc[g]);
    }
    __syncthreads();
  }
  const float* bp = bq + ((size_t)d * 256 + j0) * 4;
#pragma unroll
  for (int g = 0; g < 16; ++g) {
    int jj = g >> 2, q = g & 3;
    Gq[gq_off(t, d, j0 + jj, q, sb)] = acc[g] + bp[g];
  }
}

// ---------------- K2: rstep v6 — acc[8], 8 waves/SIMD ----------------
// grid 1024 = [sg 32][d 2][jsl 16]; block 512 = (kh 4)(sq 2)(64 lanes).
// Thread: lane=(jl,q); 8 s per thread; K-quarter 64.
__global__ __launch_bounds__(512, 8) void k_rstep(
    const float* __restrict__ wt4, const float* __restrict__ Gq,
    float* __restrict__ ht_f, float* __restrict__ ht_b,
    float* __restrict__ ct, int t) {
  __shared__ float red[3][128][9];     // kh=1..3 partials, 13.8 KB
  __shared__ float gb[4][16][17];      // gates [q][jl][s16], 4.4 KB
  const int tid = threadIdx.x;
  const int bid = blockIdx.x;
  const int jsl = bid & 15, d = (bid >> 4) & 1, sg = bid >> 5;   // sg 0..31
  const int kh = __builtin_amdgcn_readfirstlane(tid >> 7);       // 0..3
  const int sq = __builtin_amdgcn_readfirstlane((tid >> 6) & 1); // 0..1
  const int rem = tid & 127;
  const int lane = tid & 63;
  const int j0 = jsl * 16;
  const int s0 = sg * 16 + sq * 8;
  const int tt = d ? 31 - t : t;

  float* htX = d ? ht_b : ht_f;
  const float* hprev = htX + (size_t)t * HT;                 // [k 256][s 512]
  const float* wp = wt4 + ((size_t)d * 256 + (size_t)kh * 64) * 1024 + j0 * 4 + lane;
  const float* hp = hprev + (size_t)kh * 64 * 512 + s0;

  float acc[8];
#pragma unroll
  for (int i = 0; i < 8; ++i) acc[i] = 0.f;

#pragma unroll 4
  for (int k = 0; k < 64; ++k) {
    const float w = wp[(size_t)k * 1024];                    // per-lane, coalesced
    const float* h = hp + (size_t)k * 512;                   // wave-uniform
    float4 h0_ = *(const float4*)(h);
    float4 h1_ = *(const float4*)(h + 4);
    acc[0] = fmaf(w, h0_.x, acc[0]);
    acc[1] = fmaf(w, h0_.y, acc[1]);
    acc[2] = fmaf(w, h0_.z, acc[2]);
    acc[3] = fmaf(w, h0_.w, acc[3]);
    acc[4] = fmaf(w, h1_.x, acc[4]);
    acc[5] = fmaf(w, h1_.y, acc[5]);
    acc[6] = fmaf(w, h1_.z, acc[6]);
    acc[7] = fmaf(w, h1_.w, acc[7]);
  }

  if (kh > 0) {
#pragma unroll
    for (int i = 0; i < 8; ++i) red[kh - 1][rem][i] = acc[i];
  }
  __syncthreads();
  if (kh == 0) {
    const int jl = lane >> 2, q = lane & 3;
#pragma unroll
    for (int i = 0; i < 8; ++i) {
      float v = acc[i] + red[0][rem][i] + red[1][rem][i] + red[2][rem][i];
      gb[q][jl][sq * 8 + i] = v;
    }
  }
  __syncthreads();

  // pointwise: 256 cells (16 j x 16 s), tid < 256
  if (tid < 256) {
    const int jl2 = tid >> 4, sp = tid & 15;
    const int j = j0 + jl2;
    const int s = sg * 16 + sp;
    const float* gp = Gq + gq_off(tt, d, j, 0, s);
    float gi = gb[0][jl2][sp] + gp[0];
    float gf = gb[1][jl2][sp] + gp[512];
    float gg = gb[2][jl2][sp] + gp[1024];
    float go = gb[3][jl2][sp] + gp[1536];
    float si = 1.f / (1.f + expf(-gi));
    float sf = 1.f / (1.f + expf(-gf));
    float tg = tanhf(gg);
    float so = 1.f / (1.f + expf(-go));
    const size_t coff = ((size_t)d * 256 + j) * 512 + s;
    float cp = ct[coff];
    float cn = sf * cp + si * tg;
    float hn = so * tanhf(cn);
    ct[coff] = cn;
    htX[(size_t)(t + 1) * HT + (size_t)j * 512 + s] = hn;
  }
}

// ---------------- K3: featsT = [hf|hb]@w_out^T + b_out ----------------
__global__ __launch_bounds__(256) void k_out(
    const float* __restrict__ ht_f, const float* __restrict__ ht_b,
    const float* __restrict__ wot, const float* __restrict__ b_out,
    float* __restrict__ featsT) {
  __shared__ float red[4][11][64];
  const int tid = threadIdx.x;
  const int bid = blockIdx.x;
  const int t = bid >> 3, stile = bid & 7;
  const int wid = __builtin_amdgcn_readfirstlane(tid >> 6);
  const int lane = tid & 63;
  const int s0 = stile * 64;
  const int kg0 = wid * 128;
  const float* src = (wid < 2)
      ? ht_f + (size_t)(t + 1) * HT + (size_t)kg0 * 512
      : ht_b + (size_t)(32 - t) * HT + (size_t)(kg0 - 256) * 512;

  float acc[11];
#pragma unroll
  for (int g = 0; g < 11; ++g) acc[g] = 0.f;
#pragma unroll 4
  for (int kk = 0; kk < 128; ++kk) {
    float a = src[(size_t)kk * 512 + s0 + lane];
    const float* wp = wot + (size_t)(kg0 + kk) * 11;
#pragma unroll
    for (int g = 0; g < 11; ++g) acc[g] = fmaf(a, wp[g], acc[g]);
  }
#pragma unroll
  for (int g = 0; g < 11; ++g) red[wid][g][lane] = acc[g];
  __syncthreads();
  if (wid == 0) {
#pragma unroll
    for (int g = 0; g < 11; ++g) {
      float v = red[0][g][lane] + red[1][g][lane] + red[2][g][lane] +
                red[3][g][lane] + b_out[g];
      featsT[(size_t)g * 16384 + t * 512 + s0 + lane] = v;
    }
  }
}

// ---------------- K4: Viterbi v4 — readlane broadcast + packed psi ----------------
__global__ __launch_bounds__(128) void k_viterbi(const float* __restrict__ featsT,
                                                 const float* __restrict__ trans,
                                                 float* __restrict__ out) {
  __shared__ float fl[512 * T_];
  __shared__ unsigned psiP[128][12];          // 4 steps packed per word
  __shared__ unsigned char specL[121 * 47];
  __shared__ unsigned char selL[16];
  __shared__ int lastL;
  __shared__ float scoreL;
  const int b = blockIdx.x, tid = threadIdx.x;
  for (int i = tid; i < 512 * T_; i += 128) {
    int tag = i >> 9, s = i & 511;
    fl[s * T_ + tag] = featsT[(size_t)tag * 16384 + b * 512 + s];
  }
  __syncthreads();

  if (tid < 64) {
    const int lane = tid;
    const int to = (lane < T_) ? lane : 0;
    float tr[T_];
#pragma unroll
    for (int f = 0; f < T_; ++f) tr[f] = trans[to * T_ + f];
    float delta = (lane == 9) ? 0.f : -10000.f;   // START=9
    unsigned pk = 0;

    for (int s = 1; s < 512; ++s) {
      float fv = fl[s * T_ + to];
      float v0 = tr[0] + rdlane(delta, 0);
      float v1 = tr[1] + rdlane(delta, 1);
      float v2 = tr[2] + rdlane(delta, 2);
      float v3 = tr[3] + rdlane(delta, 3);
      float v4 = tr[4] + rdlane(delta, 4);
      float v5 = tr[5] + rdlane(delta, 5);
      float v6 = tr[6] + rdlane(delta, 6);
      float v7 = tr[7] + rdlane(delta, 7);
      float v8 = tr[8] + rdlane(delta, 8);
      float v9 = tr[9] + rdlane(delta, 9);
      float v10 = tr[10] + rdlane(delta, 10);
      float mA = fmaxf(fmaxf(v0, v1), v2);
      float mB = fmaxf(fmaxf(v3, v4), v5);
      float mC = fmaxf(fmaxf(v6, v7), v8);
      float mD = fmaxf(v9, v10);
      float m = fmaxf(fmaxf(mA, mB), fmaxf(mC, mD));
      delta = m + fv;
      unsigned msk = (v0 == m) ? 1u : 0u;
      msk |= (v1 == m) ? 2u : 0u;
      msk |= (v2 == m) ? 4u : 0u;
      msk |= (v3 == m) ? 8u : 0u;
      msk |= (v4 == m) ? 16u : 0u;
      msk |= (v5 == m) ? 32u : 0u;
      msk |= (v6 == m) ? 64u : 0u;
      msk |= (v7 == m) ? 128u : 0u;
      msk |= (v8 == m) ? 256u : 0u;
      msk |= (v9 == m) ? 512u : 0u;
      msk |= (v10 == m) ? 1024u : 0u;
      unsigned am = (unsigned)(__ffs(msk) - 1);
      const int r = (s - 1) & 3;
      pk |= am << (r * 8);
      if (r == 3) {
        if (lane < T_) psiP[(s - 1) >> 2][lane] = pk;
        pk = 0;
      }
    }
    if (lane < T_) psiP[127][lane] = pk;   // k = 508..510

    float d0 = rdlane(delta, 0), d1 = rdlane(delta, 1);
    float d2 = rdlane(delta, 2), d3 = rdlane(delta, 3);
    float d4 = rdlane(delta, 4), d5 = rdlane(delta, 5);
    float d6 = rdlane(delta, 6), d7 = rdlane(delta, 7);
    float d8 = rdlane(delta, 8), d9 = rdlane(delta, 9);
    float d10 = rdlane(delta, 10);
    float mA = fmaxf(fmaxf(d0, d1), d2);
    float mB = fmaxf(fmaxf(d3, d4), d5);
    float mC = fmaxf(fmaxf(d6, d7), d8);
    float mD = fmaxf(d9, d10);
    float m = fmaxf(fmaxf(mA, mB), fmaxf(mC, mD));
    unsigned msk = (d0 == m) ? 1u : 0u;
    msk |= (d1 == m) ? 2u : 0u;
    msk |= (d2 == m) ? 4u : 0u;
    msk |= (d3 == m) ? 8u : 0u;
    msk |= (d4 == m) ? 16u : 0u;
    msk |= (d5 == m) ? 32u : 0u;
    msk |= (d6 == m) ? 64u : 0u;
    msk |= (d7 == m) ? 128u : 0u;
    msk |= (d8 == m) ? 256u : 0u;
    msk |= (d9 == m) ? 512u : 0u;
    msk |= (d10 == m) ? 1024u : 0u;
    int am = __ffs(msk) - 1;
    if (lane == 0) { lastL = am; scoreL = m; }
  }
  __syncthreads();

  const int last = lastL;
  if (tid < 121) {
    const int g = tid / 11, tau = tid - g * 11;
    const int khi = 510 - 47 * g;
    const int len = (g < 10) ? 47 : 41;
    int cur = tau;
    unsigned char* sp = &specL[(g * 11 + tau) * 47];
    for (int i = 0; i < len; ++i) {
      const int k = khi - i;
      cur = (int)((psiP[k >> 2][cur] >> ((k & 3) * 8)) & 0xffu);
      sp[i] = (unsigned char)cur;
    }
  }
  __syncthreads();
  if (tid == 0) {
    int cur = last;
    for (int g = 0; g < 11; ++g) {
      selL[g] = (unsigned char)cur;
      int len = (g < 10) ? 47 : 41;
      cur = specL[(g * 11 + cur) * 47 + (len - 1)];
    }
    out[b] = scoreL;
    out[32 + (size_t)b * 512 + 511] = (float)last;
  }
  __syncthreads();
  if (tid < 121) {
    const int g = tid / 11, tau = tid - g * 11;
    if (tau == selL[g]) {
      const int khi = 510 - 47 * g;
      const int len = (g < 10) ? 47 : 41;
      float* path = out + 32 + (size_t)b * 512;
      const unsigned char* sp = &specL[(g * 11 + tau) * 47];
      for (int i = 0; i < len; ++i) path[khi - i] = (float)sp[i];
    }
  }
}

}  // namespace

extern "C" void kernel_launch(void* const* d_in, const int* in_sizes, int n_in,
                              void* d_out, int out_size, void* d_ws, size_t ws_size,
                              hipStream_t stream) {
  const int* sent     = (const int*)d_in[0];
  const float* embed  = (const float*)d_in[1];
  const float* w_ih_f = (const float*)d_in[2];
  const float* w_hh_f = (const float*)d_in[3];
  const float* b_ih_f = (const float*)d_in[4];
  const float* b_hh_f = (const float*)d_in[5];
  const float* w_ih_b = (const float*)d_in[6];
  const float* w_hh_b = (const float*)d_in[7];
  const float* b_ih_b = (const float*)d_in[8];
  const float* b_hh_b = (const float*)d_in[9];
  const float* h0     = (const float*)d_in[10];
  const float* c0     = (const float*)d_in[11];
  const float* w_out  = (const float*)d_in[12];
  const float* b_out  = (const float*)d_in[13];
  const float* trans  = (const float*)d_in[14];

  float* ws = (float*)d_ws;
  float* Gq     = ws;                      // 33,554,432
  float* ht_f   = Gq + 33554432;           //  4,325,376  (33 slabs)
  float* ht_b   = ht_f + 4325376;          //  4,325,376
  float* ct     = ht_b + 4325376;          //    262,144
  float* wiq    = ct + 262144;             //    524,288
  float* wt4    = wiq + 524288;            //    524,288
  float* bq     = wt4 + 524288;            //      2,048
  float* wot    = bq + 2048;               //      5,632
  float* featsT = wot + 5632;              //    180,224
  // total 43,703,808 floats = 166.7 MiB

  k_prep<<<6174, 256, 0, stream>>>(w_ih_f, w_ih_b, w_hh_f, w_hh_b,
                                   b_ih_f, b_hh_f, b_ih_b, b_hh_b,
                                   h0, c0, w_out,
                                   wiq, wt4, bq, ct, ht_f, ht_b, wot);
  k_ggemm<<<8192, 256, 0, stream>>>(sent, embed, wiq, bq, Gq);
  for (int t = 0; t < 32; ++t)
    k_rstep<<<1024, 512, 0, stream>>>(wt4, Gq, ht_f, ht_b, ct, t);
  k_out<<<256, 256, 0, stream>>>(ht_f, ht_b, wot, b_out, featsT);
  k_viterbi<<<32, 128, 0, stream>>>(featsT, trans, (float*)d_out);
}

// Round 17
// 747.416 us; speedup vs baseline: 1.3000x; 1.3000x over previous
//
#include <hip/hip_runtime.h>
#include <math.h>

// BiLSTM-CRF fp32, round 17.
// rstep reverted to v4 (proven 13us/step; v6 occupancy theory refuted).
// ggemm v6: 2 rows per lane (128-row tile) -> W s_load bytes per FMA halved,
// 32 FMA per kk iteration. Everything else = round-15 proven config.
// Output: d_out[0:32]=score, d_out[32:32+16384]=path (floats).

namespace {

constexpr int T_ = 11;
constexpr int HT = 256 * 512;        // one h slab (j-major, s-innermost)

__device__ __forceinline__ size_t gq_off(int t, int d, int j, int q, int s) {
  return ((((size_t)(t * 2 + d) * 256 + j) * 4 + q) * 512 + s);
}

__device__ __forceinline__ float rdlane(float v, int l) {
  return __uint_as_float(__builtin_amdgcn_readlane(__float_as_uint(v), l));
}

// ---------------- K0: prep (transposes), flat 1,580,544 elements ----------------
__global__ __launch_bounds__(256) void k_prep(
    const float* __restrict__ w_ih_f, const float* __restrict__ w_ih_b,
    const float* __restrict__ w_hh_f, const float* __restrict__ w_hh_b,
    const float* __restrict__ b_ih_f, const float* __restrict__ b_hh_f,
    const float* __restrict__ b_ih_b, const float* __restrict__ b_hh_b,
    const float* __restrict__ h0, const float* __restrict__ c0,
    const float* __restrict__ w_out,
    float* __restrict__ wiq, float* __restrict__ wt4, float* __restrict__ bq,
    float* __restrict__ ct, float* __restrict__ ht_f, float* __restrict__ ht_b,
    float* __restrict__ wot) {
  const int i = blockIdx.x * 256 + threadIdx.x;
  if (i < 524288) {                                    // wiq from w_ih
    int d = i >> 18, r = i & 262143, gcr = r >> 8, k = r & 255;
    int q = gcr >> 8, j = gcr & 255;
    const float* w = d ? w_ih_b : w_ih_f;
    wiq[((size_t)(d * 256 + k) * 256 + j) * 4 + q] = w[gcr * 256 + k];
  } else if (i < 1048576) {                            // wt4 from w_hh (same fmt)
    int i2 = i - 524288;
    int d = i2 >> 18, r = i2 & 262143, gcr = r >> 8, k = r & 255;
    int q = gcr >> 8, j = gcr & 255;
    const float* w = d ? w_hh_b : w_hh_f;
    wt4[((size_t)(d * 256 + k) * 256 + j) * 4 + q] = w[gcr * 256 + k];
  } else if (i < 1050624) {                            // bq
    int r = i - 1048576;
    int d = r >> 10, x = r & 1023, j = x >> 2, q = x & 3;
    const float* bi = d ? b_ih_b : b_ih_f;
    const float* bh = d ? b_hh_b : b_hh_f;
    bq[r] = bi[q * 256 + j] + bh[q * 256 + j];
  } else if (i < 1312768) {                            // ct from c0
    int r = i - 1050624;
    int d = r >> 17, y = r & 131071, j = y >> 9, s = y & 511;
    ct[r] = c0[((size_t)d * 512 + s) * 256 + j];
  } else if (i < 1574912) {                            // ht slot 0 from h0
    int r = i - 1312768;
    int d = r >> 17, y = r & 131071, j = y >> 9, s = y & 511;
    float v = h0[((size_t)d * 512 + s) * 256 + j];
    if (d == 0) ht_f[y] = v; else ht_b[y] = v;
  } else if (i < 1580544) {                            // wot from w_out
    int r = i - 1574912;
    int k = r / 11, tag = r - k * 11;
    wot[r] = w_out[tag * 512 + k];
  }
}

// ---------------- K1: ggemm v6 — 128-row tile, 2 rows/lane ----------------
// grid 4096 = [rt 128][d 2][jg4 16]; 256 thr = 4 waves; wave: 128 rows x 16 gc.
__global__ __launch_bounds__(256) void k_ggemm(
    const int* __restrict__ sent, const float* __restrict__ embed,
    const float* __restrict__ wiq, const float* __restrict__ bq,
    float* __restrict__ Gq) {
  __shared__ float As[64][129];        // [k][row], 33 KB
  const int tid = threadIdx.x;
  const int bid = blockIdx.x;
  const int jg4 = bid & 15;
  const int d = (bid >> 4) & 1;
  const int rt = bid >> 5;             // 0..127
  const int wid = __builtin_amdgcn_readfirstlane(tid >> 6);
  const int lane = tid & 63;
  const int row0 = rt * 128;
  const int t = row0 >> 9;             // uniform (128 | 512)
  const int sb = (row0 & 511) + lane;  // lane's rows: sb and sb+64
  const int j0 = (jg4 * 4 + wid) * 4;

  // staging: 2 threads per row (k-halves), scatter As[k][row]
  const int r2 = tid & 127, khalf = tid >> 7;
  const int tok = sent[row0 + r2];
  const float* erow = embed + (size_t)tok * 256 + khalf * 32;

  float acc[32];
#pragma unroll
  for (int g = 0; g < 32; ++g) acc[g] = 0.f;

  const float* wbase = wiq + (size_t)d * 262144;

  for (int ci = 0; ci < 4; ++ci) {
    const int k0 = ci * 64;
    const float* ep = erow + k0;
    const int kb = khalf * 32;
#pragma unroll
    for (int v = 0; v < 8; ++v) {
      float4 x4 = *(const float4*)(ep + v * 4);
      As[kb + v * 4 + 0][r2] = x4.x;
      As[kb + v * 4 + 1][r2] = x4.y;
      As[kb + v * 4 + 2][r2] = x4.z;
      As[kb + v * 4 + 3][r2] = x4.w;
    }
    __syncthreads();
#pragma unroll 4
    for (int kk = 0; kk < 64; ++kk) {
      float a0 = As[kk][lane];
      float a1 = As[kk][lane + 64];
      const float* wp = wbase + (size_t)(k0 + kk) * 1024 + j0 * 4;  // uniform
#pragma unroll
      for (int g = 0; g < 16; ++g) {
        float w = wp[g];
        acc[g]      = fmaf(a0, w, acc[g]);
        acc[16 + g] = fmaf(a1, w, acc[16 + g]);
      }
    }
    __syncthreads();
  }
  const float* bp = bq + ((size_t)d * 256 + j0) * 4;
#pragma unroll
  for (int g = 0; g < 16; ++g) {
    int jj = g >> 2, q = g & 3;
    float b = bp[g];
    size_t o = gq_off(t, d, j0 + jj, q, sb);
    Gq[o]      = acc[g] + b;
    Gq[o + 64] = acc[16 + g] + b;
  }
}

// ---------------- K2: rstep v4 (round-10/15, proven) ----------------
// grid 512 = [sg 16][d 2][jsl 16]; block 512 = (kh 4) x (sq 2) x 64 lanes.
__global__ __launch_bounds__(512, 4) void k_rstep(
    const float* __restrict__ wt4, const float* __restrict__ Gq,
    float* __restrict__ ht_f, float* __restrict__ ht_b,
    float* __restrict__ ct, int t) {
  __shared__ float red[3][128][17];    // kh=1..3 partials
  __shared__ float gb[4][16][33];      // gates [q][jl][s32]
  const int tid = threadIdx.x;
  const int bid = blockIdx.x;
  const int jsl = bid & 15, d = (bid >> 4) & 1, sg = bid >> 5;   // sg 0..15
  const int kh = __builtin_amdgcn_readfirstlane(tid >> 7);       // 0..3
  const int sq = __builtin_amdgcn_readfirstlane((tid >> 6) & 1); // 0..1
  const int rem = tid & 127;
  const int lane = tid & 63;
  const int j0 = jsl * 16;
  const int s0 = sg * 32 + sq * 16;
  const int tt = d ? 31 - t : t;

  float* htX = d ? ht_b : ht_f;
  const float* hprev = htX + (size_t)t * HT;                 // [k 256][s 512]
  const float* wp = wt4 + ((size_t)d * 256 + (size_t)kh * 64) * 1024 + j0 * 4 + lane;
  const float* hp = hprev + (size_t)kh * 64 * 512 + s0;

  float acc[16];
#pragma unroll
  for (int i = 0; i < 16; ++i) acc[i] = 0.f;

#pragma unroll 4
  for (int k = 0; k < 64; ++k) {
    const float w = wp[(size_t)k * 1024];                    // per-lane, coalesced
    const float* h = hp + (size_t)k * 512;                   // wave-uniform
    float4 h0_ = *(const float4*)(h);
    float4 h1_ = *(const float4*)(h + 4);
    float4 h2_ = *(const float4*)(h + 8);
    float4 h3_ = *(const float4*)(h + 12);
    acc[0]  = fmaf(w, h0_.x, acc[0]);
    acc[1]  = fmaf(w, h0_.y, acc[1]);
    acc[2]  = fmaf(w, h0_.z, acc[2]);
    acc[3]  = fmaf(w, h0_.w, acc[3]);
    acc[4]  = fmaf(w, h1_.x, acc[4]);
    acc[5]  = fmaf(w, h1_.y, acc[5]);
    acc[6]  = fmaf(w, h1_.z, acc[6]);
    acc[7]  = fmaf(w, h1_.w, acc[7]);
    acc[8]  = fmaf(w, h2_.x, acc[8]);
    acc[9]  = fmaf(w, h2_.y, acc[9]);
    acc[10] = fmaf(w, h2_.z, acc[10]);
    acc[11] = fmaf(w, h2_.w, acc[11]);
    acc[12] = fmaf(w, h3_.x, acc[12]);
    acc[13] = fmaf(w, h3_.y, acc[13]);
    acc[14] = fmaf(w, h3_.z, acc[14]);
    acc[15] = fmaf(w, h3_.w, acc[15]);
  }

  if (kh > 0) {
#pragma unroll
    for (int i = 0; i < 16; ++i) red[kh - 1][rem][i] = acc[i];
  }
  __syncthreads();
  if (kh == 0) {
    const int jl = lane >> 2, q = lane & 3;
#pragma unroll
    for (int i = 0; i < 16; ++i) {
      float v = acc[i] + red[0][rem][i] + red[1][rem][i] + red[2][rem][i];
      gb[q][jl][sq * 16 + i] = v;
    }
  }
  __syncthreads();

  // pointwise: 512 cells (16 j x 32 s), 1 per thread
  {
    const int jl2 = tid >> 5, sp = tid & 31;
    const int j = j0 + jl2;
    const int s = sg * 32 + sp;
    const float* gp = Gq + gq_off(tt, d, j, 0, s);
    float gi = gb[0][jl2][sp] + gp[0];
    float gf = gb[1][jl2][sp] + gp[512];
    float gg = gb[2][jl2][sp] + gp[1024];
    float go = gb[3][jl2][sp] + gp[1536];
    float si = 1.f / (1.f + expf(-gi));
    float sf = 1.f / (1.f + expf(-gf));
    float tg = tanhf(gg);
    float so = 1.f / (1.f + expf(-go));
    const size_t coff = ((size_t)d * 256 + j) * 512 + s;
    float cp = ct[coff];
    float cn = sf * cp + si * tg;
    float hn = so * tanhf(cn);
    ct[coff] = cn;
    htX[(size_t)(t + 1) * HT + (size_t)j * 512 + s] = hn;
  }
}

// ---------------- K3: featsT = [hf|hb]@w_out^T + b_out ----------------
__global__ __launch_bounds__(256) void k_out(
    const float* __restrict__ ht_f, const float* __restrict__ ht_b,
    const float* __restrict__ wot, const float* __restrict__ b_out,
    float* __restrict__ featsT) {
  __shared__ float red[4][11][64];
  const int tid = threadIdx.x;
  const int bid = blockIdx.x;
  const int t = bid >> 3, stile = bid & 7;
  const int wid = __builtin_amdgcn_readfirstlane(tid >> 6);
  const int lane = tid & 63;
  const int s0 = stile * 64;
  const int kg0 = wid * 128;
  const float* src = (wid < 2)
      ? ht_f + (size_t)(t + 1) * HT + (size_t)kg0 * 512
      : ht_b + (size_t)(32 - t) * HT + (size_t)(kg0 - 256) * 512;

  float acc[11];
#pragma unroll
  for (int g = 0; g < 11; ++g) acc[g] = 0.f;
#pragma unroll 4
  for (int kk = 0; kk < 128; ++kk) {
    float a = src[(size_t)kk * 512 + s0 + lane];
    const float* wp = wot + (size_t)(kg0 + kk) * 11;
#pragma unroll
    for (int g = 0; g < 11; ++g) acc[g] = fmaf(a, wp[g], acc[g]);
  }
#pragma unroll
  for (int g = 0; g < 11; ++g) red[wid][g][lane] = acc[g];
  __syncthreads();
  if (wid == 0) {
#pragma unroll
    for (int g = 0; g < 11; ++g) {
      float v = red[0][g][lane] + red[1][g][lane] + red[2][g][lane] +
                red[3][g][lane] + b_out[g];
      featsT[(size_t)g * 16384 + t * 512 + s0 + lane] = v;
    }
  }
}

// ---------------- K4: Viterbi v4 — readlane broadcast + packed psi ----------------
__global__ __launch_bounds__(128) void k_viterbi(const float* __restrict__ featsT,
                                                 const float* __restrict__ trans,
                                                 float* __restrict__ out) {
  __shared__ float fl[512 * T_];
  __shared__ unsigned psiP[128][12];          // 4 steps packed per word
  __shared__ unsigned char specL[121 * 47];
  __shared__ unsigned char selL[16];
  __shared__ int lastL;
  __shared__ float scoreL;
  const int b = blockIdx.x, tid = threadIdx.x;
  for (int i = tid; i < 512 * T_; i += 128) {
    int tag = i >> 9, s = i & 511;
    fl[s * T_ + tag] = featsT[(size_t)tag * 16384 + b * 512 + s];
  }
  __syncthreads();

  if (tid < 64) {
    const int lane = tid;
    const int to = (lane < T_) ? lane : 0;
    float tr[T_];
#pragma unroll
    for (int f = 0; f < T_; ++f) tr[f] = trans[to * T_ + f];
    float delta = (lane == 9) ? 0.f : -10000.f;   // START=9
    unsigned pk = 0;

    for (int s = 1; s < 512; ++s) {
      float fv = fl[s * T_ + to];
      float v0 = tr[0] + rdlane(delta, 0);
      float v1 = tr[1] + rdlane(delta, 1);
      float v2 = tr[2] + rdlane(delta, 2);
      float v3 = tr[3] + rdlane(delta, 3);
      float v4 = tr[4] + rdlane(delta, 4);
      float v5 = tr[5] + rdlane(delta, 5);
      float v6 = tr[6] + rdlane(delta, 6);
      float v7 = tr[7] + rdlane(delta, 7);
      float v8 = tr[8] + rdlane(delta, 8);
      float v9 = tr[9] + rdlane(delta, 9);
      float v10 = tr[10] + rdlane(delta, 10);
      float mA = fmaxf(fmaxf(v0, v1), v2);
      float mB = fmaxf(fmaxf(v3, v4), v5);
      float mC = fmaxf(fmaxf(v6, v7), v8);
      float mD = fmaxf(v9, v10);
      float m = fmaxf(fmaxf(mA, mB), fmaxf(mC, mD));
      delta = m + fv;
      unsigned msk = (v0 == m) ? 1u : 0u;
      msk |= (v1 == m) ? 2u : 0u;
      msk |= (v2 == m) ? 4u : 0u;
      msk |= (v3 == m) ? 8u : 0u;
      msk |= (v4 == m) ? 16u : 0u;
      msk |= (v5 == m) ? 32u : 0u;
      msk |= (v6 == m) ? 64u : 0u;
      msk |= (v7 == m) ? 128u : 0u;
      msk |= (v8 == m) ? 256u : 0u;
      msk |= (v9 == m) ? 512u : 0u;
      msk |= (v10 == m) ? 1024u : 0u;
      unsigned am = (unsigned)(__ffs(msk) - 1);
      const int r = (s - 1) & 3;
      pk |= am << (r * 8);
      if (r == 3) {
        if (lane < T_) psiP[(s - 1) >> 2][lane] = pk;
        pk = 0;
      }
    }
    if (lane < T_) psiP[127][lane] = pk;   // k = 508..510

    float d0 = rdlane(delta, 0), d1 = rdlane(delta, 1);
    float d2 = rdlane(delta, 2), d3 = rdlane(delta, 3);
    float d4 = rdlane(delta, 4), d5 = rdlane(delta, 5);
    float d6 = rdlane(delta, 6), d7 = rdlane(delta, 7);
    float d8 = rdlane(delta, 8), d9 = rdlane(delta, 9);
    float d10 = rdlane(delta, 10);
    float mA = fmaxf(fmaxf(d0, d1), d2);
    float mB = fmaxf(fmaxf(d3, d4), d5);
    float mC = fmaxf(fmaxf(d6, d7), d8);
    float mD = fmaxf(d9, d10);
    float m = fmaxf(fmaxf(mA, mB), fmaxf(mC, mD));
    unsigned msk = (d0 == m) ? 1u : 0u;
    msk |= (d1 == m) ? 2u : 0u;
    msk |= (d2 == m) ? 4u : 0u;
    msk |= (d3 == m) ? 8u : 0u;
    msk |= (d4 == m) ? 16u : 0u;
    msk |= (d5 == m) ? 32u : 0u;
    msk |= (d6 == m) ? 64u : 0u;
    msk |= (d7 == m) ? 128u : 0u;
    msk |= (d8 == m) ? 256u : 0u;
    msk |= (d9 == m) ? 512u : 0u;
    msk |= (d10 == m) ? 1024u : 0u;
    int am = __ffs(msk) - 1;
    if (lane == 0) { lastL = am; scoreL = m; }
  }
  __syncthreads();

  const int last = lastL;
  if (tid < 121) {
    const int g = tid / 11, tau = tid - g * 11;
    const int khi = 510 - 47 * g;
    const int len = (g < 10) ? 47 : 41;
    int cur = tau;
    unsigned char* sp = &specL[(g * 11 + tau) * 47];
    for (int i = 0; i < len; ++i) {
      const int k = khi - i;
      cur = (int)((psiP[k >> 2][cur] >> ((k & 3) * 8)) & 0xffu);
      sp[i] = (unsigned char)cur;
    }
  }
  __syncthreads();
  if (tid == 0) {
    int cur = last;
    for (int g = 0; g < 11; ++g) {
      selL[g] = (unsigned char)cur;
      int len = (g < 10) ? 47 : 41;
      cur = specL[(g * 11 + cur) * 47 + (len - 1)];
    }
    out[b] = scoreL;
    out[32 + (size_t)b * 512 + 511] = (float)last;
  }
  __syncthreads();
  if (tid < 121) {
    const int g = tid / 11, tau = tid - g * 11;
    if (tau == selL[g]) {
      const int khi = 510 - 47 * g;
      const int len = (g < 10) ? 47 : 41;
      float* path = out + 32 + (size_t)b * 512;
      const unsigned char* sp = &specL[(g * 11 + tau) * 47];
      for (int i = 0; i < len; ++i) path[khi - i] = (float)sp[i];
    }
  }
}

}  // namespace

extern "C" void kernel_launch(void* const* d_in, const int* in_sizes, int n_in,
                              void* d_out, int out_size, void* d_ws, size_t ws_size,
                              hipStream_t stream) {
  const int* sent     = (const int*)d_in[0];
  const float* embed  = (const float*)d_in[1];
  const float* w_ih_f = (const float*)d_in[2];
  const float* w_hh_f = (const float*)d_in[3];
  const float* b_ih_f = (const float*)d_in[4];
  const float* b_hh_f = (const float*)d_in[5];
  const float* w_ih_b = (const float*)d_in[6];
  const float* w_hh_b = (const float*)d_in[7];
  const float* b_ih_b = (const float*)d_in[8];
  const float* b_hh_b = (const float*)d_in[9];
  const float* h0     = (const float*)d_in[10];
  const float* c0     = (const float*)d_in[11];
  const float* w_out  = (const float*)d_in[12];
  const float* b_out  = (const float*)d_in[13];
  const float* trans  = (const float*)d_in[14];

  float* ws = (float*)d_ws;
  float* Gq     = ws;                      // 33,554,432
  float* ht_f   = Gq + 33554432;           //  4,325,376  (33 slabs)
  float* ht_b   = ht_f + 4325376;          //  4,325,376
  float* ct     = ht_b + 4325376;          //    262,144
  float* wiq    = ct + 262144;             //    524,288
  float* wt4    = wiq + 524288;            //    524,288
  float* bq     = wt4 + 524288;            //      2,048
  float* wot    = bq + 2048;               //      5,632
  float* featsT = wot + 5632;              //    180,224
  // total 43,703,808 floats = 166.7 MiB

  k_prep<<<6174, 256, 0, stream>>>(w_ih_f, w_ih_b, w_hh_f, w_hh_b,
                                   b_ih_f, b_hh_f, b_ih_b, b_hh_b,
                                   h0, c0, w_out,
                                   wiq, wt4, bq, ct, ht_f, ht_b, wot);
  k_ggemm<<<4096, 256, 0, stream>>>(sent, embed, wiq, bq, Gq);
  for (int t = 0; t < 32; ++t)
    k_rstep<<<512, 512, 0, stream>>>(wt4, Gq, ht_f, ht_b, ct, t);
  k_out<<<256, 256, 0, stream>>>(ht_f, ht_b, wot, b_out, featsT);
  k_viterbi<<<32, 128, 0, stream>>>(featsT, trans, (float*)d_out);
}